// Round 1
// baseline (577.480 us; speedup 1.0000x reference)
//
#include <hip/hip_runtime.h>
#include <math.h>

namespace {

constexpr float kC1 = 0.0001f;   // (0.01 * 1.0)^2
constexpr float kC2 = 0.0009f;   // (0.03 * 1.0)^2

enum Quant { QX, QY, QX2, QY2, QXY, QL1 };

// Normalized 1D Gaussian half-kernel (symmetric), computed per-thread into
// registers (all indices compile-time after unroll). Truncation tail < 2e-8
// relative for R<16; R=16 is the full 33-tap filter.
template<int R>
__device__ __forceinline__ void make_w(float sigma, float (&w)[R + 1]) {
  const float inv2s2 = 1.0f / (2.0f * sigma * sigma);
#pragma unroll
  for (int k = 0; k <= R; ++k) w[k] = expf(-(float)(k * k) * inv2s2);
  float s = w[0];
#pragma unroll
  for (int k = 1; k <= R; ++k) s += 2.0f * w[k];
  const float inv = 1.0f / s;
#pragma unroll
  for (int k = 0; k <= R; ++k) w[k] *= inv;
}

// Horizontal blur of derived quantity Q over the 64-row halo tile.
// 512 entries (64 rows x 8 col-groups), each entry = 4 consecutive output
// cols, sliding-window register blocking: (2R+4)-ish float window read as
// aligned float4s, 4*(2R+1) FMAs.
template<int R, int Q>
__device__ __forceinline__ void hpass(const float (&sA)[64][64], const float (&sB)[64][64],
                                      float (&hb)[64][32], const float (&w)[R + 1], int t) {
  constexpr int QS = (16 - R) & ~3;                 // aligned window start (rel. to c0)
  constexpr int NW = ((19 + R - QS) / 4 + 1) * 4;   // window floats (multiple of 4)
#pragma unroll 1
  for (int e = 0; e < 2; ++e) {
    const int entry = t + (e << 8);
    const int row = entry >> 3;
    const int c0 = (entry & 7) << 2;
    float win[NW];
#pragma unroll
    for (int j4 = 0; j4 < NW / 4; ++j4) {
      float4 a4 = make_float4(0.f, 0.f, 0.f, 0.f);
      float4 b4 = make_float4(0.f, 0.f, 0.f, 0.f);
      if constexpr (Q == QX || Q == QX2 || Q == QXY || Q == QL1)
        a4 = *reinterpret_cast<const float4*>(&sA[row][c0 + QS + 4 * j4]);
      if constexpr (Q == QY || Q == QY2 || Q == QXY || Q == QL1)
        b4 = *reinterpret_cast<const float4*>(&sB[row][c0 + QS + 4 * j4]);
      const float* ap = reinterpret_cast<const float*>(&a4);
      const float* bp = reinterpret_cast<const float*>(&b4);
#pragma unroll
      for (int u = 0; u < 4; ++u) {
        float v;
        if constexpr (Q == QX)       v = ap[u];
        else if constexpr (Q == QY)  v = bp[u];
        else if constexpr (Q == QX2) v = ap[u] * ap[u];
        else if constexpr (Q == QY2) v = bp[u] * bp[u];
        else if constexpr (Q == QXY) v = ap[u] * bp[u];
        else                         v = fabsf(ap[u] - bp[u]);
        win[4 * j4 + u] = v;
      }
    }
    float acc[4] = {0.f, 0.f, 0.f, 0.f};
#pragma unroll
    for (int jj = 0; jj < NW; ++jj) {
      const float v = win[jj];
#pragma unroll
      for (int o = 0; o < 4; ++o) {
        const int k = QS + jj - 16 - o;   // compile-time after unroll
        if (k >= -R && k <= R) acc[o] += v * w[(k < 0) ? -k : k];
      }
    }
    *reinterpret_cast<float4*>(&hb[row][c0]) = make_float4(acc[0], acc[1], acc[2], acc[3]);
  }
}

// Vertical blur: each thread owns 4 consecutive rows of one column.
// Column b32 reads: bank = col = lane&31 -> conflict-free (2-way is free).
template<int R>
__device__ __forceinline__ void vpass(const float (&hb)[64][32], const float (&w)[R + 1],
                                      int vc, int vr0, float (&out)[4]) {
#pragma unroll
  for (int i = 0; i < 4; ++i) out[i] = 0.f;
#pragma unroll
  for (int jj = 0; jj < 2 * R + 4; ++jj) {
    const float v = hb[vr0 + 16 - R + jj][vc];
#pragma unroll
    for (int i = 0; i < 4; ++i) {
      const int k = jj - R - i;
      if (k >= -R && k <= R) out[i] += v * w[(k < 0) ? -k : k];
    }
  }
}

template<int R, int Q>
__device__ __forceinline__ void blur1(const float (&sA)[64][64], const float (&sB)[64][64],
                                      float (&hb)[64][32], const float (&w)[R + 1],
                                      int t, int vc, int vr0, float (&out)[4]) {
  hpass<R, Q>(sA, sB, hb, w, t);
  __syncthreads();
  vpass<R>(hb, w, vc, vr0, out);
  __syncthreads();
}

// One (sigma, channel) combo: blur x, y, x^2, y^2, xy; fold cs^mult into PI;
// optionally lM (sigma=8, ch=2) and the sigma=8 L1 blur.
template<int R>
__device__ __forceinline__ void phase5(float sigma, int mult, bool doLM, bool doL1,
                                       const float (&sA)[64][64], const float (&sB)[64][64],
                                       float (&hb)[64][32], int t, int vc, int vr0,
                                       float (&PI)[4], float (&lM)[4], float (&l1s)[4]) {
  float w[R + 1];
  make_w<R>(sigma, w);
  float mx[4], my[4], ex2[4], ey2[4], exy[4];
  blur1<R, QX >(sA, sB, hb, w, t, vc, vr0, mx);
  blur1<R, QY >(sA, sB, hb, w, t, vc, vr0, my);
  blur1<R, QX2>(sA, sB, hb, w, t, vc, vr0, ex2);
  blur1<R, QY2>(sA, sB, hb, w, t, vc, vr0, ey2);
  blur1<R, QXY>(sA, sB, hb, w, t, vc, vr0, exy);
  if (doL1) {
    float g[4];
    blur1<R, QL1>(sA, sB, hb, w, t, vc, vr0, g);
#pragma unroll
    for (int i = 0; i < 4; ++i) l1s[i] += g[i];
  }
#pragma unroll
  for (int i = 0; i < 4; ++i) {
    const float vx  = ex2[i] - mx[i] * mx[i];
    const float vy  = ey2[i] - my[i] * my[i];
    const float vxy = exy[i] - mx[i] * my[i];
    const float cs  = (2.f * vxy + kC2) / (vx + vy + kC2);
    float p = cs;
    if (mult > 1) p *= cs;
    if (mult > 2) p *= cs;
    PI[i] *= p;
    if (doLM) {
      const float lc = (2.f * mx[i] * my[i] + kC1) /
                       (mx[i] * mx[i] + my[i] * my[i] + kC1);
      lM[i] = lc * lc * lc;
    }
  }
}

template<int R>
__device__ __forceinline__ void phaseL1(float sigma,
                                        const float (&sA)[64][64], const float (&sB)[64][64],
                                        float (&hb)[64][32], int t, int vc, int vr0,
                                        float (&l1s)[4]) {
  float w[R + 1];
  make_w<R>(sigma, w);
  float g[4];
  blur1<R, QL1>(sA, sB, hb, w, t, vc, vr0, g);
#pragma unroll
  for (int i = 0; i < 4; ++i) l1s[i] += g[i];
}

}  // namespace

// One block per (batch b, 32x32 output tile). Loads 64x64 halo tiles of both
// images for each channel, runs the per-channel sigma phases, accumulates the
// per-pixel loss across channels in registers, block-reduces, writes one
// partial per block into d_ws (deterministic; no float atomics).
extern "C" __global__ __launch_bounds__(256) void msssim_main(
    const float* __restrict__ img1, const float* __restrict__ img2,
    float* __restrict__ partial) {
  __shared__ __align__(16) float sA[64][64];
  __shared__ __align__(16) float sB[64][64];
  __shared__ __align__(16) float hb[64][32];

  const int t = threadIdx.x;
  const int b = blockIdx.z;
  const int gx0 = (int)blockIdx.x * 32 - 16;
  const int gy0 = (int)blockIdx.y * 32 - 16;
  const int vc = t & 31;          // owned column in tile
  const int vr0 = (t >> 5) << 2;  // owned row base (4 consecutive rows)

  float PI[4]  = {1.f, 1.f, 1.f, 1.f};
  float lM[4]  = {0.f, 0.f, 0.f, 0.f};
  float l1s[4] = {0.f, 0.f, 0.f, 0.f};

  for (int ch = 0; ch < 3; ++ch) {
    const float* p1 = img1 + (((size_t)b * 3 + ch) << 18);
    const float* p2 = img2 + (((size_t)b * 3 + ch) << 18);
    __syncthreads();
#pragma unroll
    for (int e = 0; e < 16; ++e) {
      const int idx = t + (e << 8);
      const int ly = idx >> 6, lx = idx & 63;
      const int gy = gy0 + ly, gx = gx0 + lx;
      const bool inb = (gy >= 0) & (gy < 512) & (gx >= 0) & (gx < 512);
      sA[ly][lx] = inb ? p1[(gy << 9) + gx] : 0.f;  // zero padding, as reference
      sB[ly][lx] = inb ? p2[(gy << 9) + gx] : 0.f;
    }
    __syncthreads();

    // Group-conv mapping: output channel o -> sigma SIGMAS[o/3], input ch o/5.
    // Distinct combos & multiplicities:
    //   ch0: s0.5^3, s1^2        (+ L1 s8)
    //   ch1: s1^1, s2^3, s4^1    (+ L1 s8)
    //   ch2: s4^2, s8^3 (+ lM from lc_s8^3, + L1 s8 fused)
    if (ch == 0) {
      phase5<2>(0.5f, 3, false, false, sA, sB, hb, t, vc, vr0, PI, lM, l1s);
      phase5<5>(1.0f, 2, false, false, sA, sB, hb, t, vc, vr0, PI, lM, l1s);
      phaseL1<16>(8.0f, sA, sB, hb, t, vc, vr0, l1s);
    } else if (ch == 1) {
      phase5<5>(1.0f, 1, false, false, sA, sB, hb, t, vc, vr0, PI, lM, l1s);
      phase5<11>(2.0f, 3, false, false, sA, sB, hb, t, vc, vr0, PI, lM, l1s);
      phase5<16>(4.0f, 1, false, false, sA, sB, hb, t, vc, vr0, PI, lM, l1s);
      phaseL1<16>(8.0f, sA, sB, hb, t, vc, vr0, l1s);
    } else {
      phase5<16>(4.0f, 2, false, false, sA, sB, hb, t, vc, vr0, PI, lM, l1s);
      phase5<16>(8.0f, 3, true, true, sA, sB, hb, t, vc, vr0, PI, lM, l1s);
    }
  }

  // loss = alpha*(1 - lM*PIcs) + (1-alpha)*mean_ch(gaussian_l1)
  float s = 0.f;
#pragma unroll
  for (int i = 0; i < 4; ++i)
    s += 0.025f * (1.f - lM[i] * PI[i]) + 0.975f * (l1s[i] * (1.f / 3.f));

  // block reduce (wave shuffle + LDS), one partial per block
#pragma unroll
  for (int off = 32; off >= 1; off >>= 1) s += __shfl_down(s, off, 64);
  __syncthreads();
  float* red = &hb[0][0];
  if ((t & 63) == 0) red[t >> 6] = s;
  __syncthreads();
  if (t == 0) {
    partial[((size_t)blockIdx.z * gridDim.y + blockIdx.y) * gridDim.x + blockIdx.x] =
        red[0] + red[1] + red[2] + red[3];
  }
}

extern "C" __global__ __launch_bounds__(256) void msssim_reduce(
    const float* __restrict__ partial, float* __restrict__ out, int n) {
  __shared__ float red[4];
  float s = 0.f;
  for (int i = threadIdx.x; i < n; i += 256) s += partial[i];
#pragma unroll
  for (int off = 32; off >= 1; off >>= 1) s += __shfl_down(s, off, 64);
  if ((threadIdx.x & 63) == 0) red[threadIdx.x >> 6] = s;
  __syncthreads();
  if (threadIdx.x == 0) {
    // mean over 8*512*512 pixels, times COMPENSATION=200
    out[0] = (red[0] + red[1] + red[2] + red[3]) * (200.0f / 2097152.0f);
  }
}

extern "C" void kernel_launch(void* const* d_in, const int* in_sizes, int n_in,
                              void* d_out, int out_size, void* d_ws, size_t ws_size,
                              hipStream_t stream) {
  const float* img1 = (const float*)d_in[0];
  const float* img2 = (const float*)d_in[1];
  float* out = (float*)d_out;
  float* partial = (float*)d_ws;  // 2048 floats

  dim3 grid(16, 16, 8);  // (tileX, tileY, batch)
  msssim_main<<<grid, dim3(256), 0, stream>>>(img1, img2, partial);
  msssim_reduce<<<1, dim3(256), 0, stream>>>(partial, out, 2048);
}